// Round 13
// baseline (1588.269 us; speedup 1.0000x reference)
//
#include <hip/hip_runtime.h>
#include <hip/hip_bf16.h>
#include <math.h>

// dims
constexpr int B_ = 64, S_ = 512, LP_ = 18, CE_ = 10, LF_ = 32;
constexpr int WE_ = 200, H_ = 200, T_ = 64;
constexpr int N_ = B_ * S_;        // 32768 tokens, n = b*S + s = t*64 + j
constexpr int KP_ = 256;           // padded K for proj GEMM (232 -> 256)
constexpr int G4_ = 800;           // 4*H
constexpr int NG_ = 1600;          // both directions stacked
constexpr int NGP_ = 1664;         // padded to 13*128 for the 128-tile GEMM
constexpr float L2E_ = 1.4426950408889634f;

typedef short short8 __attribute__((ext_vector_type(8)));
typedef float f32x4 __attribute__((ext_vector_type(4)));

__device__ __forceinline__ ushort bf16bits(float v) {
  return __bfloat16_as_ushort(__float2bfloat16(v));
}
__device__ __forceinline__ float bf2f(ushort u) {
  return __uint_as_float(((uint)u) << 16);
}
__device__ __forceinline__ float exp2fast(float x) {
  float r; asm("v_exp_f32 %0, %1" : "=v"(r) : "v"(x)); return r;
}
// sigmoid with input pre-scaled by log2e:  sig2(y) = 1/(1+2^-y)
__device__ __forceinline__ float sig2(float y) {
  return __builtin_amdgcn_rcpf(1.f + exp2fast(-y));
}

// ---------------- K1: char CNN + embeddings -> Xb [N, 256] bf16 (zero-padded) ----------------
__global__ __launch_bounds__(256) void k_build_x(
    const int* __restrict__ char_ids, const int* __restrict__ word_ids,
    const float* __restrict__ word_emb, const float* __restrict__ char_emb,
    const float* __restrict__ conv_w, const float* __restrict__ conv_b,
    ushort* __restrict__ Xb)
{
  __shared__ float ce[4][LP_ * CE_];
  const int wave = threadIdx.x >> 6, lane = threadIdx.x & 63;
  const int n = blockIdx.x * 4 + wave;

  for (int i = lane; i < LP_ * CE_; i += 64) {
    int c = char_ids[n * LP_ + i / CE_];
    ce[wave][i] = char_emb[c * CE_ + (i % CE_)];
  }
  const float* we = word_emb + (size_t)word_ids[n] * WE_;
  ushort* xr = Xb + (size_t)n * KP_;
  for (int i = lane; i < WE_; i += 64) xr[i] = bf16bits(we[i]);
  if (lane < KP_ - WE_ - LF_) xr[WE_ + LF_ + lane] = 0;   // pad cols 232..255
  __syncthreads();

  const int f = lane & 31, half = lane >> 5;
  float cw[30];
  #pragma unroll
  for (int i = 0; i < 30; ++i) cw[i] = conv_w[f * 30 + i];
  float m = -1e30f;
  for (int w = half * 8; w < half * 8 + 8; ++w) {
    float acc = 0.f;
    #pragma unroll
    for (int i = 0; i < 30; ++i) acc += ce[wave][w * CE_ + i] * cw[i];
    m = fmaxf(m, acc);
  }
  m = fmaxf(m, __shfl_xor(m, 32));
  if (half == 0) xr[WE_ + f] = bf16bits(m + conv_b[f]);
}

// ---------------- pack W_ih (both dirs) -> Wb [1664][256] bf16, biasc [1664] f32 ----------------
// Rows pre-scaled by log2e (i,f,o gates) / 2*log2e (g gate). Rows >= 1600 zero-filled.
__global__ __launch_bounds__(64) void k_pack_w(
    const float* __restrict__ w_ih_f, const float* __restrict__ w_ih_b,
    const float* __restrict__ b_ih_f, const float* __restrict__ b_hh_f,
    const float* __restrict__ b_ih_b, const float* __restrict__ b_hh_b,
    ushort* __restrict__ Wb, float* __restrict__ biasc)
{
  const int r = blockIdx.x;  // 0..1663
  if (r >= NG_) {
    for (int c = threadIdx.x; c < KP_; c += 64) Wb[(size_t)r * KP_ + c] = 0;
    if (threadIdx.x == 0) biasc[r] = 0.f;
    return;
  }
  const int rl = r < G4_ ? r : r - G4_;
  const int gate = rl / 200;
  const float sc = (gate == 2) ? 2.f * L2E_ : L2E_;
  const float* src = r < G4_ ? w_ih_f + (size_t)rl * 232 : w_ih_b + (size_t)rl * 232;
  for (int c = threadIdx.x; c < KP_; c += 64)
    Wb[(size_t)r * KP_ + c] = (c < 232) ? bf16bits(src[c] * sc) : (ushort)0;
  if (threadIdx.x == 0)
    biasc[r] = sc * (r < G4_ ? (b_ih_f[rl] + b_hh_f[rl]) : (b_ih_b[rl] + b_hh_b[rl]));
}

// ---------------- K2: MFMA GEMM  Gc[n][1600] = Xb @ Wb^T + bias (bf16 out) ----------------
// 128x128 tile, K=256 in one LDS stage (A 64KB + B 64KB). 512 thr = 8 waves,
// wave (wr=w>>2, wc=w&3) owns a 64x32 quadrant (4x2 16x16 frags x 8 kt = 64 MFMA).
__global__ __launch_bounds__(512) void k_gemm_proj(
    const ushort* __restrict__ Xb, const ushort* __restrict__ Wb,
    const float* __restrict__ biasc, ushort* __restrict__ Gc)
{
  __shared__ __align__(16) char smem[131072];   // A: 0..64K (swz), B: 64K..128K (swz)
  const int tid = threadIdx.x;
  const int lane = tid & 63, w = tid >> 6;
  const int wr = w >> 2, wc = w & 3;
  const int colbase = blockIdx.x * 128;     // 0..1536 (13 tiles, padded Wb)
  const int rowbase = blockIdx.y * 128;     // 0..32640

  // stage A,B tiles (128 rows x 512B each) with XOR swizzle
  const char* Ag = (const char*)(Xb + (size_t)rowbase * KP_);
  const char* Bg = (const char*)(Wb + (size_t)colbase * KP_);
  #pragma unroll
  for (int it = 0; it < 8; ++it) {
    int slot = it * 512 + tid;              // 0..4095
    int row = slot >> 5, c16 = slot & 31;
    int src = row * 512 + c16 * 16;
    int dst = row * 512 + ((c16 * 16) ^ ((row & 7) << 4));
    *(short8*)(smem + dst) = *(const short8*)(Ag + src);
    *(short8*)(smem + 65536 + dst) = *(const short8*)(Bg + src);
  }
  __syncthreads();

  f32x4 acc[4][2] = {};
  #pragma unroll
  for (int kk = 0; kk < 8; ++kk) {
    const int kb = kk * 64 + (lane >> 4) * 16;
    short8 a[4], b[2];
    #pragma unroll
    for (int m = 0; m < 4; ++m) {
      int ar = wr * 64 + m * 16 + (lane & 15);
      a[m] = *(const short8*)(smem + ar * 512 + (kb ^ ((ar & 7) << 4)));
    }
    #pragma unroll
    for (int n = 0; n < 2; ++n) {
      int bc = wc * 32 + n * 16 + (lane & 15);
      b[n] = *(const short8*)(smem + 65536 + bc * 512 + (kb ^ ((bc & 7) << 4)));
    }
    #pragma unroll
    for (int m = 0; m < 4; ++m)
      #pragma unroll
      for (int n = 0; n < 2; ++n)
        acc[m][n] = __builtin_amdgcn_mfma_f32_16x16x32_bf16(a[m], b[n], acc[m][n], 0, 0, 0);
  }
  __syncthreads();

  // dump acc -> Cs[128][132] f32 (aliases smem), then vectorized bf16 stores
  float* Cs = (float*)smem;
  #pragma unroll
  for (int m = 0; m < 4; ++m)
    #pragma unroll
    for (int n = 0; n < 2; ++n)
      #pragma unroll
      for (int i = 0; i < 4; ++i) {
        int r = wr * 64 + m * 16 + (lane >> 4) * 4 + i;
        int c = wc * 32 + n * 16 + (lane & 15);
        Cs[r * 132 + c] = acc[m][n][i];
      }
  __syncthreads();

  const int r = tid >> 2, cg = (tid & 3) * 32;
  ushort ob[32];
  #pragma unroll
  for (int j = 0; j < 32; ++j)
    ob[j] = bf16bits(Cs[r * 132 + cg + j] + biasc[colbase + cg + j]);
  const int colg = colbase + cg;
  ushort* dst = Gc + (size_t)(rowbase + r) * NG_ + colg;
  #pragma unroll
  for (int v = 0; v < 4; ++v)
    if (colg + v * 8 < NG_)                 // 1600 % 8 == 0 -> clean per-vec mask
      *(short8*)(dst + v * 8) = *(short8*)(ob + v * 8);
}

// ---------------- K3: LSTM recurrence v12 (frozen champion, 1236 us) ----------------
// 16 blocks = 2 dirs x 8 chain-groups(8 real chains). 1024 thr = 16 waves (4/SIMD).
// Wave w owns ONE unit-slot. Weights kt0..3 in regs, kt4/5 in LDS, kt6 in LDS with
// zero-block. h double-buffered in LDS. Single __syncthreads per step.
// NONLIN SPLIT: lanes lo<8 handle cells i={0,1}, lanes lo>=8 handle i={2,3}.
__global__ __launch_bounds__(1024) void k_lstm(
    const ushort* __restrict__ Gc,
    const float* __restrict__ w_hh_f, const float* __restrict__ w_hh_b,
    ushort* __restrict__ hf, ushort* __restrict__ hb)
{
  __shared__ ushort h_lds[2][16][232];                 // 14,848 B
  __shared__ __align__(16) char wlds45[2][65536];      // kt4,kt5: gid*1024 + lane*16
  __shared__ __align__(16) char wlds6[17408];          // kt6: gid*256 + lo*16 (hi==0); [16384..17408) zeros

  const int tid = threadIdx.x;
  const int lane = tid & 63, w = tid >> 6;             // w = slot, 0..15
  const int lo = lane & 15, hi = lane >> 4;
  const bool hiHalf = lo >= 8;                         // owns cells i=2,3
  const int dir = blockIdx.x >> 3, grp = blockIdx.x & 7;
  const float* Whh = dir ? w_hh_b : w_hh_f;
  ushort* hout = dir ? hb : hf;

  for (int i = tid; i < 2 * 16 * 232; i += 1024) ((ushort*)h_lds)[i] = 0;
  if (tid < 256) ((uint*)(wlds6 + 16384))[tid] = 0;

  const int s = w;
  const int off = s < 12 ? 12 * s : 144 + 16 * (s - 12);
  const int cnt = s < 12 ? 12 : 16;
  const int rl  = min(cnt, 200 - off);

  // ---- prologue: weights (pre-scaled by log2e / 2log2e) into regs + LDS ----
  short8 wreg[4][4];   // [gate][kt0..3]
  #pragma unroll
  for (int g = 0; g < 4; ++g) {
    const float sc = (g == 2) ? 2.f * L2E_ : L2E_;
    const float* wr = Whh + (size_t)(g * 200 + off + lo) * 200;
    const bool rowok = lo < rl;
    const int gid = s * 4 + g;
    #pragma unroll
    for (int kt = 0; kt < 7; ++kt) {
      const int k0 = kt * 32 + hi * 8;
      float v[8];
      if (rowok && k0 < 200) {
        float4 p0 = *(const float4*)(wr + k0);
        float4 p1 = *(const float4*)(wr + k0 + 4);
        v[0] = p0.x; v[1] = p0.y; v[2] = p0.z; v[3] = p0.w;
        v[4] = p1.x; v[5] = p1.y; v[6] = p1.z; v[7] = p1.w;
      } else {
        #pragma unroll
        for (int j = 0; j < 8; ++j) v[j] = 0.f;
      }
      short8 fr;
      #pragma unroll
      for (int j = 0; j < 8; ++j) fr[j] = (short)bf16bits(v[j] * sc);
      if (kt < 4) wreg[g][kt] = fr;
      else if (kt < 6) *(short8*)(wlds45[kt - 4] + gid * 1024 + lane * 16) = fr;
      else if (hi == 0) *(short8*)(wlds6 + gid * 256 + lo * 16) = fr;
    }
  }

  float c2_[2] = {0.f, 0.f};   // owned cells only (i0,i1 for lo<8; i2,i3 for lo>=8)

  // step-invariant addressing
  const int rowsel = lo & 7;                       // pad lanes duplicate a real row
  const int step0 = dir ? (S_ - 1) : 0;
  const ushort* gpp = Gc + (size_t)(step0 * 64 + grp * 8 + rowsel) * NG_ + dir * G4_ + off + hi * 4;
  ushort* sp = hout + (size_t)(step0 * 64 + grp * 8 + rowsel) * H_ + off + hi * 4 + (hiHalf ? 2 : 0);
  const ptrdiff_t gstep = (dir ? -64 : 64) * (ptrdiff_t)NG_;
  const ptrdiff_t hstep = (dir ? -64 : 64) * (ptrdiff_t)H_;
  const bool cellok = (hi * 4 < rl);               // rl multiple of 4 -> same both halves
  const int hwoff = rowsel * 464 + off * 2 + hi * 8 + (hiHalf ? 4 : 0);

  const char* base45a = wlds45[0] + s * 4096 + lane * 16;
  const char* base45b = wlds45[1] + s * 4096 + lane * 16;
  const char* base6   = wlds6 + ((hi == 0) ? (s * 1024 + lo * 16) : (16384 + lo * 16));

  __syncthreads();   // weights + zeroed h/zero-block visible

  #pragma unroll 2
  for (int t = 0; t < S_; ++t) {
    const ushort (*HR)[232] = h_lds[t & 1];
    ushort (*HW)[232] = h_lds[(t & 1) ^ 1];

    // preact loads for this step (in flight across the MFMA phase)
    uint2 pre[4];
    #pragma unroll
    for (int g = 0; g < 4; ++g)
      pre[g] = *(const uint2*)(gpp + g * 200);

    // ---- MFMA phase ----
    __builtin_amdgcn_s_setprio(1);
    f32x4 acc[4] = {};
    const char* hrow = (const char*)HR + lo * 464 + hi * 16;
    #pragma unroll
    for (int kt = 0; kt < 7; ++kt) {
      short8 hfr = *(const short8*)(hrow + kt * 64);
      if (kt < 4) {
        #pragma unroll
        for (int g = 0; g < 4; ++g)
          acc[g] = __builtin_amdgcn_mfma_f32_16x16x32_bf16(wreg[g][kt], hfr, acc[g], 0, 0, 0);
      } else if (kt == 4) {
        #pragma unroll
        for (int g = 0; g < 4; ++g) {
          short8 wk = *(const short8*)(base45a + g * 1024);
          acc[g] = __builtin_amdgcn_mfma_f32_16x16x32_bf16(wk, hfr, acc[g], 0, 0, 0);
        }
      } else if (kt == 5) {
        #pragma unroll
        for (int g = 0; g < 4; ++g) {
          short8 wk = *(const short8*)(base45b + g * 1024);
          acc[g] = __builtin_amdgcn_mfma_f32_16x16x32_bf16(wk, hfr, acc[g], 0, 0, 0);
        }
      } else {
        #pragma unroll
        for (int g = 0; g < 4; ++g) {
          short8 wk = *(const short8*)(base6 + g * 256);
          acc[g] = __builtin_amdgcn_mfma_f32_16x16x32_bf16(wk, hfr, acc[g], 0, 0, 0);
        }
      }
    }
    __builtin_amdgcn_s_setprio(0);

    // ---- lane-split nonlinearity: 2 owned cells per thread ----
    const uint ui = hiHalf ? pre[0].y : pre[0].x;
    const uint uf = hiHalf ? pre[1].y : pre[1].x;
    const uint ug = hiHalf ? pre[2].y : pre[2].x;
    const uint uo = hiHalf ? pre[3].y : pre[3].x;
    const float aI0 = hiHalf ? acc[0][2] : acc[0][0];
    const float aI1 = hiHalf ? acc[0][3] : acc[0][1];
    const float aF0 = hiHalf ? acc[1][2] : acc[1][0];
    const float aF1 = hiHalf ? acc[1][3] : acc[1][1];
    const float aG0 = hiHalf ? acc[2][2] : acc[2][0];
    const float aG1 = hiHalf ? acc[2][3] : acc[2][1];
    const float aO0 = hiHalf ? acc[3][2] : acc[3][0];
    const float aO1 = hiHalf ? acc[3][3] : acc[3][1];

    float hv0, hv1;
    {
      float gi = aI0 + bf2f((ushort)ui);
      float gf = aF0 + bf2f((ushort)uf);
      float gg = aG0 + bf2f((ushort)ug);
      float go = aO0 + bf2f((ushort)uo);
      float cn = sig2(gf) * c2_[0] + sig2(gi) * (2.f * sig2(gg) - 1.f);
      c2_[0] = cn;
      hv0 = sig2(go) * (2.f * sig2(cn * (2.f * L2E_)) - 1.f);
    }
    {
      float gi = aI1 + bf2f((ushort)(ui >> 16));
      float gf = aF1 + bf2f((ushort)(uf >> 16));
      float gg = aG1 + bf2f((ushort)(ug >> 16));
      float go = aO1 + bf2f((ushort)(uo >> 16));
      float cn = sig2(gf) * c2_[1] + sig2(gi) * (2.f * sig2(gg) - 1.f);
      c2_[1] = cn;
      hv1 = sig2(go) * (2.f * sig2(cn * (2.f * L2E_)) - 1.f);
    }
    const uint pkw = (uint)bf16bits(hv0) | ((uint)bf16bits(hv1) << 16);
    if (cellok) {
      *(uint*)((char*)HW + hwoff) = pkw;   // LDS next-buffer (b32, all lanes useful)
    }

    __syncthreads();   // h visible; loads/stores long retired

    if (cellok) *(uint*)sp = pkw;          // global bf16 h, fire-and-forget
    sp += hstep;
    gpp += gstep;
  }
}

// ---------------- K4: tag = [hf|hb](bf16) @ out_w^T + out_b ----------------
__global__ __launch_bounds__(256) void k_out(
    const ushort* __restrict__ hf, const ushort* __restrict__ hb,
    const float* __restrict__ out_w, const float* __restrict__ out_b,
    float* __restrict__ tag)
{
  const int m = threadIdx.x >> 3;
  const int tg = threadIdx.x & 7;
  const int n = blockIdx.x * 32 + m;
  const ushort* hfp = hf + (size_t)n * H_;
  const ushort* hbp = hb + (size_t)n * H_;
  float acc[8];
  #pragma unroll
  for (int q = 0; q < 8; ++q) acc[q] = out_b[tg + 8 * q];
  for (int k = 0; k < H_ / 4; ++k) {
    uint2 hv = *(const uint2*)(hfp + k * 4);
    float x0 = bf2f((ushort)hv.x), x1 = bf2f((ushort)(hv.x >> 16));
    float x2 = bf2f((ushort)hv.y), x3 = bf2f((ushort)(hv.y >> 16));
    #pragma unroll
    for (int q = 0; q < 8; ++q) {
      float4 w = ((const float4*)(out_w + (size_t)(tg + 8 * q) * 2 * H_))[k];
      acc[q] += x0 * w.x + x1 * w.y + x2 * w.z + x3 * w.w;
    }
  }
  for (int k = 0; k < H_ / 4; ++k) {
    uint2 hv = *(const uint2*)(hbp + k * 4);
    float x0 = bf2f((ushort)hv.x), x1 = bf2f((ushort)(hv.x >> 16));
    float x2 = bf2f((ushort)hv.y), x3 = bf2f((ushort)(hv.y >> 16));
    #pragma unroll
    for (int q = 0; q < 8; ++q) {
      float4 w = ((const float4*)(out_w + (size_t)(tg + 8 * q) * 2 * H_ + H_))[k];
      acc[q] += x0 * w.x + x1 * w.y + x2 * w.z + x3 * w.w;
    }
  }
  #pragma unroll
  for (int q = 0; q < 8; ++q) tag[(size_t)n * T_ + tg + 8 * q] = acc[q];
}

// ---------------- K5: log_softmax over the sequence axis (dim=1) ----------------
__global__ __launch_bounds__(256) void k_lsm(
    const float* __restrict__ tag, float* __restrict__ out)
{
  __shared__ float red[4][T_];
  __shared__ float lse[T_];
  const int b = blockIdx.x;
  const int tt = threadIdx.x & 63, ch = threadIdx.x >> 6;
  const float* tb = tag + (size_t)b * S_ * T_;

  float m = -1e30f;
  for (int s = ch * 128; s < ch * 128 + 128; ++s) m = fmaxf(m, tb[s * T_ + tt]);
  red[ch][tt] = m;
  __syncthreads();
  if (ch == 0)
    lse[tt] = fmaxf(fmaxf(red[0][tt], red[1][tt]), fmaxf(red[2][tt], red[3][tt]));
  __syncthreads();
  m = lse[tt];
  float sum = 0.f;
  for (int s = ch * 128; s < ch * 128 + 128; ++s) sum += __expf(tb[s * T_ + tt] - m);
  __syncthreads();
  red[ch][tt] = sum;
  __syncthreads();
  if (ch == 0)
    lse[tt] = m + logf(red[0][tt] + red[1][tt] + red[2][tt] + red[3][tt]);
  __syncthreads();
  const float l = lse[tt];
  float* ob = out + (size_t)b * S_ * T_;
  for (int s = ch * 128; s < ch * 128 + 128; ++s) ob[s * T_ + tt] = tb[s * T_ + tt] - l;
}

// ---------------- launch ----------------
extern "C" void kernel_launch(void* const* d_in, const int* in_sizes, int n_in,
                              void* d_out, int out_size, void* d_ws, size_t ws_size,
                              hipStream_t stream) {
  const int*   char_ids = (const int*)d_in[0];
  const int*   word_ids = (const int*)d_in[1];
  const float* word_emb = (const float*)d_in[2];
  const float* char_emb = (const float*)d_in[3];
  const float* conv_w   = (const float*)d_in[4];
  const float* conv_b   = (const float*)d_in[5];
  const float* w_ih_f   = (const float*)d_in[6];
  const float* w_hh_f   = (const float*)d_in[7];
  const float* b_ih_f   = (const float*)d_in[8];
  const float* b_hh_f   = (const float*)d_in[9];
  const float* w_ih_b   = (const float*)d_in[10];
  const float* w_hh_b   = (const float*)d_in[11];
  const float* b_ih_b   = (const float*)d_in[12];
  const float* b_hh_b   = (const float*)d_in[13];
  const float* out_w    = (const float*)d_in[14];
  const float* out_b    = (const float*)d_in[15];

  // ws layout (bytes)
  char* ws = (char*)d_ws;
  ushort* Xb    = (ushort*)(ws);                 // 16,777,216  [32768][256] bf16
  ushort* Wb    = (ushort*)(ws + 16777216);      //    851,968  [1664][256] bf16 (padded)
  float*  biasc = (float*) (ws + 17629184);      //      6,656  [1664] f32 (padded)
  ushort* Gc    = (ushort*)(ws + 18422016);      // 104,857,600 [32768][1600] bf16
  ushort* hf    = (ushort*)(ws + 123279616);     // 13,107,200  [32768][200] bf16
  ushort* hb    = (ushort*)(ws + 136386816);     // 13,107,200
  float*  tag   = (float*) (ws + 149494016);     //  8,388,608  -> total 157,882,624

  hipLaunchKernelGGL(k_build_x, dim3(N_ / 4), dim3(256), 0, stream,
                     char_ids, word_ids, word_emb, char_emb, conv_w, conv_b, Xb);
  hipLaunchKernelGGL(k_pack_w, dim3(NGP_), dim3(64), 0, stream,
                     w_ih_f, w_ih_b, b_ih_f, b_hh_f, b_ih_b, b_hh_b, Wb, biasc);
  hipLaunchKernelGGL(k_gemm_proj, dim3(NGP_ / 128, N_ / 128), dim3(512), 0, stream,
                     Xb, Wb, biasc, Gc);
  hipLaunchKernelGGL(k_lstm, dim3(16), dim3(1024), 0, stream, Gc, w_hh_f, w_hh_b, hf, hb);
  hipLaunchKernelGGL(k_out, dim3(N_ / 32), dim3(256), 0, stream, hf, hb, out_w, out_b, tag);
  hipLaunchKernelGGL(k_lsm, dim3(B_), dim3(256), 0, stream, tag, (float*)d_out);
}

// Round 14
// 1417.640 us; speedup vs baseline: 1.1204x; 1.1204x over previous
//
#include <hip/hip_runtime.h>
#include <hip/hip_bf16.h>
#include <math.h>

// dims
constexpr int B_ = 64, S_ = 512, LP_ = 18, CE_ = 10, LF_ = 32;
constexpr int WE_ = 200, H_ = 200, T_ = 64;
constexpr int N_ = B_ * S_;        // 32768 tokens, n = b*S + s = t*64 + j
constexpr int KP_ = 256;           // padded K for proj GEMM (232 -> 256)
constexpr int G4_ = 800;           // 4*H
constexpr int NG_ = 1600;          // both directions stacked
constexpr int NGP_ = 1664;         // padded to 13*128 for the 128-tile GEMM
constexpr float L2E_ = 1.4426950408889634f;

typedef short short8 __attribute__((ext_vector_type(8)));
typedef float f32x4 __attribute__((ext_vector_type(4)));

__device__ __forceinline__ ushort bf16bits(float v) {
  return __bfloat16_as_ushort(__float2bfloat16(v));
}
__device__ __forceinline__ float bf2f(ushort u) {
  return __uint_as_float(((uint)u) << 16);
}
__device__ __forceinline__ float exp2fast(float x) {
  float r; asm("v_exp_f32 %0, %1" : "=v"(r) : "v"(x)); return r;
}
// sigmoid with input pre-scaled by log2e:  sig2(y) = 1/(1+2^-y)
__device__ __forceinline__ float sig2(float y) {
  return __builtin_amdgcn_rcpf(1.f + exp2fast(-y));
}

// ---------------- K1: char CNN + embeddings -> Xb [N, 256] bf16 (zero-padded) ----------------
__global__ __launch_bounds__(256) void k_build_x(
    const int* __restrict__ char_ids, const int* __restrict__ word_ids,
    const float* __restrict__ word_emb, const float* __restrict__ char_emb,
    const float* __restrict__ conv_w, const float* __restrict__ conv_b,
    ushort* __restrict__ Xb)
{
  __shared__ float ce[4][LP_ * CE_];
  const int wave = threadIdx.x >> 6, lane = threadIdx.x & 63;
  const int n = blockIdx.x * 4 + wave;

  for (int i = lane; i < LP_ * CE_; i += 64) {
    int c = char_ids[n * LP_ + i / CE_];
    ce[wave][i] = char_emb[c * CE_ + (i % CE_)];
  }
  const float* we = word_emb + (size_t)word_ids[n] * WE_;
  ushort* xr = Xb + (size_t)n * KP_;
  // vectorized word-emb copy: 200 floats = 50 float4 -> ushort4 bf16
  if (lane < 50) {
    float4 p = *(const float4*)(we + lane * 4);
    ushort4 o;
    o.x = bf16bits(p.x); o.y = bf16bits(p.y); o.z = bf16bits(p.z); o.w = bf16bits(p.w);
    *(ushort4*)(xr + lane * 4) = o;
  }
  if (lane < KP_ - WE_ - LF_) xr[WE_ + LF_ + lane] = 0;   // pad cols 232..255
  __syncthreads();

  const int f = lane & 31, half = lane >> 5;
  float cw[30];
  #pragma unroll
  for (int i = 0; i < 30; ++i) cw[i] = conv_w[f * 30 + i];
  float m = -1e30f;
  for (int w = half * 8; w < half * 8 + 8; ++w) {
    float acc = 0.f;
    #pragma unroll
    for (int i = 0; i < 30; ++i) acc += ce[wave][w * CE_ + i] * cw[i];
    m = fmaxf(m, acc);
  }
  m = fmaxf(m, __shfl_xor(m, 32));
  if (half == 0) xr[WE_ + f] = bf16bits(m + conv_b[f]);
}

// ---------------- pack W_ih (both dirs) -> Wb [1664][256] bf16, biasc [1664] f32 ----------------
// Rows pre-scaled by log2e (i,f,o gates) / 2*log2e (g gate). Rows >= 1600 zero-filled.
__global__ __launch_bounds__(64) void k_pack_w(
    const float* __restrict__ w_ih_f, const float* __restrict__ w_ih_b,
    const float* __restrict__ b_ih_f, const float* __restrict__ b_hh_f,
    const float* __restrict__ b_ih_b, const float* __restrict__ b_hh_b,
    ushort* __restrict__ Wb, float* __restrict__ biasc)
{
  const int r = blockIdx.x;  // 0..1663
  if (r >= NG_) {
    for (int c = threadIdx.x; c < KP_; c += 64) Wb[(size_t)r * KP_ + c] = 0;
    if (threadIdx.x == 0) biasc[r] = 0.f;
    return;
  }
  const int rl = r < G4_ ? r : r - G4_;
  const int gate = rl / 200;
  const float sc = (gate == 2) ? 2.f * L2E_ : L2E_;
  const float* src = r < G4_ ? w_ih_f + (size_t)rl * 232 : w_ih_b + (size_t)rl * 232;
  for (int c = threadIdx.x; c < KP_; c += 64)
    Wb[(size_t)r * KP_ + c] = (c < 232) ? bf16bits(src[c] * sc) : (ushort)0;
  if (threadIdx.x == 0)
    biasc[r] = sc * (r < G4_ ? (b_ih_f[rl] + b_hh_f[rl]) : (b_ih_b[rl] + b_hh_b[rl]));
}

// ---------------- pack out_w -> Wo [64][416] bf16 (K padded 400 -> 416) ----------------
__global__ __launch_bounds__(64) void k_pack_wo(
    const float* __restrict__ out_w, ushort* __restrict__ Wo)
{
  const int r = blockIdx.x;   // 0..63
  for (int k = threadIdx.x; k < 416; k += 64)
    Wo[(size_t)r * 416 + k] = (k < 400) ? bf16bits(out_w[(size_t)r * 400 + k]) : (ushort)0;
}

// ---------------- K2: MFMA GEMM  Gc[n][1600] = Xb @ Wb^T + bias (bf16 out) ----------------
// 128x128 tile, K=256 in one LDS stage. 512 thr = 8 waves, wave (wr,wc) owns 64x32.
__global__ __launch_bounds__(512) void k_gemm_proj(
    const ushort* __restrict__ Xb, const ushort* __restrict__ Wb,
    const float* __restrict__ biasc, ushort* __restrict__ Gc)
{
  __shared__ __align__(16) char smem[131072];   // A: 0..64K (swz), B: 64K..128K (swz)
  const int tid = threadIdx.x;
  const int lane = tid & 63, w = tid >> 6;
  const int wr = w >> 2, wc = w & 3;
  const int colbase = blockIdx.x * 128;     // 0..1536 (13 tiles, padded Wb)
  const int rowbase = blockIdx.y * 128;     // 0..32640

  const char* Ag = (const char*)(Xb + (size_t)rowbase * KP_);
  const char* Bg = (const char*)(Wb + (size_t)colbase * KP_);
  #pragma unroll
  for (int it = 0; it < 8; ++it) {
    int slot = it * 512 + tid;              // 0..4095
    int row = slot >> 5, c16 = slot & 31;
    int src = row * 512 + c16 * 16;
    int dst = row * 512 + ((c16 * 16) ^ ((row & 7) << 4));
    *(short8*)(smem + dst) = *(const short8*)(Ag + src);
    *(short8*)(smem + 65536 + dst) = *(const short8*)(Bg + src);
  }
  __syncthreads();

  f32x4 acc[4][2] = {};
  #pragma unroll
  for (int kk = 0; kk < 8; ++kk) {
    const int kb = kk * 64 + (lane >> 4) * 16;
    short8 a[4], b[2];
    #pragma unroll
    for (int m = 0; m < 4; ++m) {
      int ar = wr * 64 + m * 16 + (lane & 15);
      a[m] = *(const short8*)(smem + ar * 512 + (kb ^ ((ar & 7) << 4)));
    }
    #pragma unroll
    for (int n = 0; n < 2; ++n) {
      int bc = wc * 32 + n * 16 + (lane & 15);
      b[n] = *(const short8*)(smem + 65536 + bc * 512 + (kb ^ ((bc & 7) << 4)));
    }
    #pragma unroll
    for (int m = 0; m < 4; ++m)
      #pragma unroll
      for (int n = 0; n < 2; ++n)
        acc[m][n] = __builtin_amdgcn_mfma_f32_16x16x32_bf16(a[m], b[n], acc[m][n], 0, 0, 0);
  }
  __syncthreads();

  float* Cs = (float*)smem;
  #pragma unroll
  for (int m = 0; m < 4; ++m)
    #pragma unroll
    for (int n = 0; n < 2; ++n)
      #pragma unroll
      for (int i = 0; i < 4; ++i) {
        int r = wr * 64 + m * 16 + (lane >> 4) * 4 + i;
        int c = wc * 32 + n * 16 + (lane & 15);
        Cs[r * 132 + c] = acc[m][n][i];
      }
  __syncthreads();

  const int r = tid >> 2, cg = (tid & 3) * 32;
  ushort ob[32];
  #pragma unroll
  for (int j = 0; j < 32; ++j)
    ob[j] = bf16bits(Cs[r * 132 + cg + j] + biasc[colbase + cg + j]);
  const int colg = colbase + cg;
  ushort* dst = Gc + (size_t)(rowbase + r) * NG_ + colg;
  #pragma unroll
  for (int v = 0; v < 4; ++v)
    if (colg + v * 8 < NG_)
      *(short8*)(dst + v * 8) = *(short8*)(ob + v * 8);
}

// ---------------- K3: LSTM recurrence v12 (frozen champion, 1236 us) ----------------
__global__ __launch_bounds__(1024) void k_lstm(
    const ushort* __restrict__ Gc,
    const float* __restrict__ w_hh_f, const float* __restrict__ w_hh_b,
    ushort* __restrict__ hf, ushort* __restrict__ hb)
{
  __shared__ ushort h_lds[2][16][232];                 // 14,848 B
  __shared__ __align__(16) char wlds45[2][65536];      // kt4,kt5: gid*1024 + lane*16
  __shared__ __align__(16) char wlds6[17408];          // kt6: gid*256 + lo*16 (hi==0); [16384..17408) zeros

  const int tid = threadIdx.x;
  const int lane = tid & 63, w = tid >> 6;             // w = slot, 0..15
  const int lo = lane & 15, hi = lane >> 4;
  const bool hiHalf = lo >= 8;                         // owns cells i=2,3
  const int dir = blockIdx.x >> 3, grp = blockIdx.x & 7;
  const float* Whh = dir ? w_hh_b : w_hh_f;
  ushort* hout = dir ? hb : hf;

  for (int i = tid; i < 2 * 16 * 232; i += 1024) ((ushort*)h_lds)[i] = 0;
  if (tid < 256) ((uint*)(wlds6 + 16384))[tid] = 0;

  const int s = w;
  const int off = s < 12 ? 12 * s : 144 + 16 * (s - 12);
  const int cnt = s < 12 ? 12 : 16;
  const int rl  = min(cnt, 200 - off);

  short8 wreg[4][4];   // [gate][kt0..3]
  #pragma unroll
  for (int g = 0; g < 4; ++g) {
    const float sc = (g == 2) ? 2.f * L2E_ : L2E_;
    const float* wr = Whh + (size_t)(g * 200 + off + lo) * 200;
    const bool rowok = lo < rl;
    const int gid = s * 4 + g;
    #pragma unroll
    for (int kt = 0; kt < 7; ++kt) {
      const int k0 = kt * 32 + hi * 8;
      float v[8];
      if (rowok && k0 < 200) {
        float4 p0 = *(const float4*)(wr + k0);
        float4 p1 = *(const float4*)(wr + k0 + 4);
        v[0] = p0.x; v[1] = p0.y; v[2] = p0.z; v[3] = p0.w;
        v[4] = p1.x; v[5] = p1.y; v[6] = p1.z; v[7] = p1.w;
      } else {
        #pragma unroll
        for (int j = 0; j < 8; ++j) v[j] = 0.f;
      }
      short8 fr;
      #pragma unroll
      for (int j = 0; j < 8; ++j) fr[j] = (short)bf16bits(v[j] * sc);
      if (kt < 4) wreg[g][kt] = fr;
      else if (kt < 6) *(short8*)(wlds45[kt - 4] + gid * 1024 + lane * 16) = fr;
      else if (hi == 0) *(short8*)(wlds6 + gid * 256 + lo * 16) = fr;
    }
  }

  float c2_[2] = {0.f, 0.f};

  const int rowsel = lo & 7;
  const int step0 = dir ? (S_ - 1) : 0;
  const ushort* gpp = Gc + (size_t)(step0 * 64 + grp * 8 + rowsel) * NG_ + dir * G4_ + off + hi * 4;
  ushort* sp = hout + (size_t)(step0 * 64 + grp * 8 + rowsel) * H_ + off + hi * 4 + (hiHalf ? 2 : 0);
  const ptrdiff_t gstep = (dir ? -64 : 64) * (ptrdiff_t)NG_;
  const ptrdiff_t hstep = (dir ? -64 : 64) * (ptrdiff_t)H_;
  const bool cellok = (hi * 4 < rl);
  const int hwoff = rowsel * 464 + off * 2 + hi * 8 + (hiHalf ? 4 : 0);

  const char* base45a = wlds45[0] + s * 4096 + lane * 16;
  const char* base45b = wlds45[1] + s * 4096 + lane * 16;
  const char* base6   = wlds6 + ((hi == 0) ? (s * 1024 + lo * 16) : (16384 + lo * 16));

  __syncthreads();

  #pragma unroll 2
  for (int t = 0; t < S_; ++t) {
    const ushort (*HR)[232] = h_lds[t & 1];
    ushort (*HW)[232] = h_lds[(t & 1) ^ 1];

    uint2 pre[4];
    #pragma unroll
    for (int g = 0; g < 4; ++g)
      pre[g] = *(const uint2*)(gpp + g * 200);

    __builtin_amdgcn_s_setprio(1);
    f32x4 acc[4] = {};
    const char* hrow = (const char*)HR + lo * 464 + hi * 16;
    #pragma unroll
    for (int kt = 0; kt < 7; ++kt) {
      short8 hfr = *(const short8*)(hrow + kt * 64);
      if (kt < 4) {
        #pragma unroll
        for (int g = 0; g < 4; ++g)
          acc[g] = __builtin_amdgcn_mfma_f32_16x16x32_bf16(wreg[g][kt], hfr, acc[g], 0, 0, 0);
      } else if (kt == 4) {
        #pragma unroll
        for (int g = 0; g < 4; ++g) {
          short8 wk = *(const short8*)(base45a + g * 1024);
          acc[g] = __builtin_amdgcn_mfma_f32_16x16x32_bf16(wk, hfr, acc[g], 0, 0, 0);
        }
      } else if (kt == 5) {
        #pragma unroll
        for (int g = 0; g < 4; ++g) {
          short8 wk = *(const short8*)(base45b + g * 1024);
          acc[g] = __builtin_amdgcn_mfma_f32_16x16x32_bf16(wk, hfr, acc[g], 0, 0, 0);
        }
      } else {
        #pragma unroll
        for (int g = 0; g < 4; ++g) {
          short8 wk = *(const short8*)(base6 + g * 256);
          acc[g] = __builtin_amdgcn_mfma_f32_16x16x32_bf16(wk, hfr, acc[g], 0, 0, 0);
        }
      }
    }
    __builtin_amdgcn_s_setprio(0);

    const uint ui = hiHalf ? pre[0].y : pre[0].x;
    const uint uf = hiHalf ? pre[1].y : pre[1].x;
    const uint ug = hiHalf ? pre[2].y : pre[2].x;
    const uint uo = hiHalf ? pre[3].y : pre[3].x;
    const float aI0 = hiHalf ? acc[0][2] : acc[0][0];
    const float aI1 = hiHalf ? acc[0][3] : acc[0][1];
    const float aF0 = hiHalf ? acc[1][2] : acc[1][0];
    const float aF1 = hiHalf ? acc[1][3] : acc[1][1];
    const float aG0 = hiHalf ? acc[2][2] : acc[2][0];
    const float aG1 = hiHalf ? acc[2][3] : acc[2][1];
    const float aO0 = hiHalf ? acc[3][2] : acc[3][0];
    const float aO1 = hiHalf ? acc[3][3] : acc[3][1];

    float hv0, hv1;
    {
      float gi = aI0 + bf2f((ushort)ui);
      float gf = aF0 + bf2f((ushort)uf);
      float gg = aG0 + bf2f((ushort)ug);
      float go = aO0 + bf2f((ushort)uo);
      float cn = sig2(gf) * c2_[0] + sig2(gi) * (2.f * sig2(gg) - 1.f);
      c2_[0] = cn;
      hv0 = sig2(go) * (2.f * sig2(cn * (2.f * L2E_)) - 1.f);
    }
    {
      float gi = aI1 + bf2f((ushort)(ui >> 16));
      float gf = aF1 + bf2f((ushort)(uf >> 16));
      float gg = aG1 + bf2f((ushort)(ug >> 16));
      float go = aO1 + bf2f((ushort)(uo >> 16));
      float cn = sig2(gf) * c2_[1] + sig2(gi) * (2.f * sig2(gg) - 1.f);
      c2_[1] = cn;
      hv1 = sig2(go) * (2.f * sig2(cn * (2.f * L2E_)) - 1.f);
    }
    const uint pkw = (uint)bf16bits(hv0) | ((uint)bf16bits(hv1) << 16);
    if (cellok) {
      *(uint*)((char*)HW + hwoff) = pkw;
    }

    __syncthreads();

    if (cellok) *(uint*)sp = pkw;
    sp += hstep;
    gpp += gstep;
  }
}

// ---------------- K4: MFMA  tag[n][64] = [hf|hb] @ Wo^T + out_b (f32 out) ----------------
// 64-token x 64-tag tile, K=416 (padded). 256 thr = 4 waves; wave w owns rows w*16..+15.
__global__ __launch_bounds__(256) void k_out(
    const ushort* __restrict__ hf, const ushort* __restrict__ hb,
    const ushort* __restrict__ Wo, const float* __restrict__ out_b,
    float* __restrict__ tag)
{
  __shared__ __align__(16) char smem[131072];  // A 64KB (rows 1024B swz), B 64KB
  const int tid = threadIdx.x;
  const int lane = tid & 63, w = tid >> 6;
  const int n0 = blockIdx.x * 64;

  // stage A: 64 rows x 52 chunks(16B): 0..24 hf row, 25..49 hb row, 50..51 zero
  for (int s2 = tid; s2 < 64 * 52; s2 += 256) {
    int row = s2 / 52, c = s2 % 52;
    short8 v = {};
    if (c < 25)      v = *(const short8*)(hf + (size_t)(n0 + row) * H_ + c * 8);
    else if (c < 50) v = *(const short8*)(hb + (size_t)(n0 + row) * H_ + (c - 25) * 8);
    *(short8*)(smem + row * 1024 + ((c ^ (row & 7)) << 4)) = v;
  }
  // stage B: Wo 64 rows x 52 chunks
  for (int s2 = tid; s2 < 64 * 52; s2 += 256) {
    int row = s2 / 52, c = s2 % 52;
    short8 v = *(const short8*)(Wo + (size_t)row * 416 + c * 8);
    *(short8*)(smem + 65536 + row * 1024 + ((c ^ (row & 7)) << 4)) = v;
  }
  __syncthreads();

  const int lo4 = lane & 15, hi4 = lane >> 4;
  f32x4 acc[4] = {};
  #pragma unroll
  for (int kt = 0; kt < 13; ++kt) {
    const int ck = kt * 4 + hi4;
    const int ar = w * 16 + lo4;
    short8 a = *(const short8*)(smem + ar * 1024 + ((ck ^ (ar & 7)) << 4));
    #pragma unroll
    for (int n = 0; n < 4; ++n) {
      const int br = n * 16 + lo4;
      short8 b = *(const short8*)(smem + 65536 + br * 1024 + ((ck ^ (br & 7)) << 4));
      acc[n] = __builtin_amdgcn_mfma_f32_16x16x32_bf16(a, b, acc[n], 0, 0, 0);
    }
  }
  #pragma unroll
  for (int n = 0; n < 4; ++n) {
    const int col = n * 16 + lo4;
    const float bb = out_b[col];
    #pragma unroll
    for (int i = 0; i < 4; ++i) {
      const int row = hi4 * 4 + i;
      tag[(size_t)(n0 + w * 16 + row) * T_ + col] = acc[n][i] + bb;
    }
  }
}

// ---------------- K5: log_softmax over the sequence axis (dim=1) ----------------
__global__ __launch_bounds__(256) void k_lsm(
    const float* __restrict__ tag, float* __restrict__ out)
{
  __shared__ float red[4][T_];
  __shared__ float lse[T_];
  const int b = blockIdx.x;
  const int tt = threadIdx.x & 63, ch = threadIdx.x >> 6;
  const float* tb = tag + (size_t)b * S_ * T_;

  float m = -1e30f;
  for (int s = ch * 128; s < ch * 128 + 128; ++s) m = fmaxf(m, tb[s * T_ + tt]);
  red[ch][tt] = m;
  __syncthreads();
  if (ch == 0)
    lse[tt] = fmaxf(fmaxf(red[0][tt], red[1][tt]), fmaxf(red[2][tt], red[3][tt]));
  __syncthreads();
  m = lse[tt];
  float sum = 0.f;
  for (int s = ch * 128; s < ch * 128 + 128; ++s) sum += __expf(tb[s * T_ + tt] - m);
  __syncthreads();
  red[ch][tt] = sum;
  __syncthreads();
  if (ch == 0)
    lse[tt] = m + logf(red[0][tt] + red[1][tt] + red[2][tt] + red[3][tt]);
  __syncthreads();
  const float l = lse[tt];
  float* ob = out + (size_t)b * S_ * T_;
  for (int s = ch * 128; s < ch * 128 + 128; ++s) ob[s * T_ + tt] = tb[s * T_ + tt] - l;
}

// ---------------- launch ----------------
extern "C" void kernel_launch(void* const* d_in, const int* in_sizes, int n_in,
                              void* d_out, int out_size, void* d_ws, size_t ws_size,
                              hipStream_t stream) {
  const int*   char_ids = (const int*)d_in[0];
  const int*   word_ids = (const int*)d_in[1];
  const float* word_emb = (const float*)d_in[2];
  const float* char_emb = (const float*)d_in[3];
  const float* conv_w   = (const float*)d_in[4];
  const float* conv_b   = (const float*)d_in[5];
  const float* w_ih_f   = (const float*)d_in[6];
  const float* w_hh_f   = (const float*)d_in[7];
  const float* b_ih_f   = (const float*)d_in[8];
  const float* b_hh_f   = (const float*)d_in[9];
  const float* w_ih_b   = (const float*)d_in[10];
  const float* w_hh_b   = (const float*)d_in[11];
  const float* b_ih_b   = (const float*)d_in[12];
  const float* b_hh_b   = (const float*)d_in[13];
  const float* out_w    = (const float*)d_in[14];
  const float* out_b    = (const float*)d_in[15];

  // ws layout (bytes)
  char* ws = (char*)d_ws;
  ushort* Xb    = (ushort*)(ws);                 // 16,777,216  [32768][256] bf16
  ushort* Wb    = (ushort*)(ws + 16777216);      //    851,968  [1664][256] bf16 (padded)
  float*  biasc = (float*) (ws + 17629184);      //      6,656  [1664] f32 (padded)
  ushort* Wo    = (ushort*)(ws + 17635840);      //     53,248  [64][416] bf16 (padded)
  ushort* Gc    = (ushort*)(ws + 18422016);      // 104,857,600 [32768][1600] bf16
  ushort* hf    = (ushort*)(ws + 123279616);     // 13,107,200  [32768][200] bf16
  ushort* hb    = (ushort*)(ws + 136386816);     // 13,107,200
  float*  tag   = (float*) (ws + 149494016);     //  8,388,608  -> total 157,882,624

  hipLaunchKernelGGL(k_build_x, dim3(N_ / 4), dim3(256), 0, stream,
                     char_ids, word_ids, word_emb, char_emb, conv_w, conv_b, Xb);
  hipLaunchKernelGGL(k_pack_w, dim3(NGP_), dim3(64), 0, stream,
                     w_ih_f, w_ih_b, b_ih_f, b_hh_f, b_ih_b, b_hh_b, Wb, biasc);
  hipLaunchKernelGGL(k_pack_wo, dim3(T_), dim3(64), 0, stream, out_w, Wo);
  hipLaunchKernelGGL(k_gemm_proj, dim3(NGP_ / 128, N_ / 128), dim3(512), 0, stream,
                     Xb, Wb, biasc, Gc);
  hipLaunchKernelGGL(k_lstm, dim3(16), dim3(1024), 0, stream, Gc, w_hh_f, w_hh_b, hf, hb);
  hipLaunchKernelGGL(k_out, dim3(N_ / 64), dim3(256), 0, stream, hf, hb, Wo, out_b, tag);
  hipLaunchKernelGGL(k_lsm, dim3(B_), dim3(256), 0, stream, tag, (float*)d_out);
}

// Round 15
// 1410.905 us; speedup vs baseline: 1.1257x; 1.0048x over previous
//
#include <hip/hip_runtime.h>
#include <hip/hip_bf16.h>
#include <math.h>

// dims
constexpr int B_ = 64, S_ = 512, LP_ = 18, CE_ = 10, LF_ = 32;
constexpr int WE_ = 200, H_ = 200, T_ = 64;
constexpr int N_ = B_ * S_;        // 32768 tokens, n = b*S + s = t*64 + j
constexpr int KP_ = 256;           // padded K for proj GEMM (232 -> 256)
constexpr int G4_ = 800;           // 4*H
constexpr int NG_ = 1600;          // both directions stacked
constexpr int NGP_ = 1664;         // padded to 13*128 for the 128-tile GEMM
constexpr float L2E_ = 1.4426950408889634f;

typedef short short8 __attribute__((ext_vector_type(8)));
typedef float f32x4 __attribute__((ext_vector_type(4)));

__device__ __forceinline__ ushort bf16bits(float v) {
  return __bfloat16_as_ushort(__float2bfloat16(v));
}
__device__ __forceinline__ float bf2f(ushort u) {
  return __uint_as_float(((uint)u) << 16);
}
__device__ __forceinline__ float exp2fast(float x) {
  float r; asm("v_exp_f32 %0, %1" : "=v"(r) : "v"(x)); return r;
}
// sigmoid with input pre-scaled by log2e:  sig2(y) = 1/(1+2^-y)
__device__ __forceinline__ float sig2(float y) {
  return __builtin_amdgcn_rcpf(1.f + exp2fast(-y));
}

// ---------------- K1: char CNN + embeddings -> Xb [N, 256] bf16 (zero-padded) ----------------
__global__ __launch_bounds__(256) void k_build_x(
    const int* __restrict__ char_ids, const int* __restrict__ word_ids,
    const float* __restrict__ word_emb, const float* __restrict__ char_emb,
    const float* __restrict__ conv_w, const float* __restrict__ conv_b,
    ushort* __restrict__ Xb)
{
  __shared__ float ce[4][LP_ * CE_];
  const int wave = threadIdx.x >> 6, lane = threadIdx.x & 63;
  const int n = blockIdx.x * 4 + wave;

  for (int i = lane; i < LP_ * CE_; i += 64) {
    int c = char_ids[n * LP_ + i / CE_];
    ce[wave][i] = char_emb[c * CE_ + (i % CE_)];
  }
  const float* we = word_emb + (size_t)word_ids[n] * WE_;
  ushort* xr = Xb + (size_t)n * KP_;
  if (lane < 50) {
    float4 p = *(const float4*)(we + lane * 4);
    ushort4 o;
    o.x = bf16bits(p.x); o.y = bf16bits(p.y); o.z = bf16bits(p.z); o.w = bf16bits(p.w);
    *(ushort4*)(xr + lane * 4) = o;
  }
  if (lane < KP_ - WE_ - LF_) xr[WE_ + LF_ + lane] = 0;   // pad cols 232..255
  __syncthreads();

  const int f = lane & 31, half = lane >> 5;
  float cw[30];
  #pragma unroll
  for (int i = 0; i < 30; ++i) cw[i] = conv_w[f * 30 + i];
  float m = -1e30f;
  for (int w = half * 8; w < half * 8 + 8; ++w) {
    float acc = 0.f;
    #pragma unroll
    for (int i = 0; i < 30; ++i) acc += ce[wave][w * CE_ + i] * cw[i];
    m = fmaxf(m, acc);
  }
  m = fmaxf(m, __shfl_xor(m, 32));
  if (half == 0) xr[WE_ + f] = bf16bits(m + conv_b[f]);
}

// ---------------- pack W_ih -> Wb [1664][256] bf16, biasc; blocks >= NGP_ pack Wo ----------------
__global__ __launch_bounds__(64) void k_pack_w(
    const float* __restrict__ w_ih_f, const float* __restrict__ w_ih_b,
    const float* __restrict__ b_ih_f, const float* __restrict__ b_hh_f,
    const float* __restrict__ b_ih_b, const float* __restrict__ b_hh_b,
    const float* __restrict__ out_w,
    ushort* __restrict__ Wb, float* __restrict__ biasc, ushort* __restrict__ Wo)
{
  const int r = blockIdx.x;  // 0..1727: [0,1664) -> Wb, [1664,1728) -> Wo
  if (r >= NGP_) {
    const int r2 = r - NGP_;   // 0..63
    for (int k = threadIdx.x; k < 416; k += 64)
      Wo[(size_t)r2 * 416 + k] = (k < 400) ? bf16bits(out_w[(size_t)r2 * 400 + k]) : (ushort)0;
    return;
  }
  if (r >= NG_) {
    for (int c = threadIdx.x; c < KP_; c += 64) Wb[(size_t)r * KP_ + c] = 0;
    if (threadIdx.x == 0) biasc[r] = 0.f;
    return;
  }
  const int rl = r < G4_ ? r : r - G4_;
  const int gate = rl / 200;
  const float sc = (gate == 2) ? 2.f * L2E_ : L2E_;
  const float* src = r < G4_ ? w_ih_f + (size_t)rl * 232 : w_ih_b + (size_t)rl * 232;
  for (int c = threadIdx.x; c < KP_; c += 64)
    Wb[(size_t)r * KP_ + c] = (c < 232) ? bf16bits(src[c] * sc) : (ushort)0;
  if (threadIdx.x == 0)
    biasc[r] = sc * (r < G4_ ? (b_ih_f[rl] + b_hh_f[rl]) : (b_ih_b[rl] + b_hh_b[rl]));
}

// ---------------- K2: MFMA GEMM  Gc[n][1600] = Xb @ Wb^T + bias (bf16 out) ----------------
// 128x128 tile, K=256 in one LDS stage. 512 thr = 8 waves, wave (wr,wc) owns 64x32.
__global__ __launch_bounds__(512) void k_gemm_proj(
    const ushort* __restrict__ Xb, const ushort* __restrict__ Wb,
    const float* __restrict__ biasc, ushort* __restrict__ Gc)
{
  __shared__ __align__(16) char smem[131072];   // A: 0..64K (swz), B: 64K..128K (swz)
  const int tid = threadIdx.x;
  const int lane = tid & 63, w = tid >> 6;
  const int wr = w >> 2, wc = w & 3;
  const int colbase = blockIdx.x * 128;     // 0..1536 (13 tiles, padded Wb)
  const int rowbase = blockIdx.y * 128;     // 0..32640

  const char* Ag = (const char*)(Xb + (size_t)rowbase * KP_);
  const char* Bg = (const char*)(Wb + (size_t)colbase * KP_);
  #pragma unroll
  for (int it = 0; it < 8; ++it) {
    int slot = it * 512 + tid;              // 0..4095
    int row = slot >> 5, c16 = slot & 31;
    int src = row * 512 + c16 * 16;
    int dst = row * 512 + ((c16 * 16) ^ ((row & 7) << 4));
    *(short8*)(smem + dst) = *(const short8*)(Ag + src);
    *(short8*)(smem + 65536 + dst) = *(const short8*)(Bg + src);
  }
  __syncthreads();

  f32x4 acc[4][2] = {};
  #pragma unroll
  for (int kk = 0; kk < 8; ++kk) {
    const int kb = kk * 64 + (lane >> 4) * 16;
    short8 a[4], b[2];
    #pragma unroll
    for (int m = 0; m < 4; ++m) {
      int ar = wr * 64 + m * 16 + (lane & 15);
      a[m] = *(const short8*)(smem + ar * 512 + (kb ^ ((ar & 7) << 4)));
    }
    #pragma unroll
    for (int n = 0; n < 2; ++n) {
      int bc = wc * 32 + n * 16 + (lane & 15);
      b[n] = *(const short8*)(smem + 65536 + bc * 512 + (kb ^ ((bc & 7) << 4)));
    }
    #pragma unroll
    for (int m = 0; m < 4; ++m)
      #pragma unroll
      for (int n = 0; n < 2; ++n)
        acc[m][n] = __builtin_amdgcn_mfma_f32_16x16x32_bf16(a[m], b[n], acc[m][n], 0, 0, 0);
  }
  __syncthreads();

  float* Cs = (float*)smem;
  #pragma unroll
  for (int m = 0; m < 4; ++m)
    #pragma unroll
    for (int n = 0; n < 2; ++n)
      #pragma unroll
      for (int i = 0; i < 4; ++i) {
        int r = wr * 64 + m * 16 + (lane >> 4) * 4 + i;
        int c = wc * 32 + n * 16 + (lane & 15);
        Cs[r * 132 + c] = acc[m][n][i];
      }
  __syncthreads();

  const int r = tid >> 2, cg = (tid & 3) * 32;
  ushort ob[32];
  #pragma unroll
  for (int j = 0; j < 32; ++j)
    ob[j] = bf16bits(Cs[r * 132 + cg + j] + biasc[colbase + cg + j]);
  const int colg = colbase + cg;
  ushort* dst = Gc + (size_t)(rowbase + r) * NG_ + colg;
  #pragma unroll
  for (int v = 0; v < 4; ++v)
    if (colg + v * 8 < NG_)
      *(short8*)(dst + v * 8) = *(short8*)(ob + v * 8);
}

// ---------------- K3: LSTM recurrence v12 (frozen champion, 1233 us) ----------------
__global__ __launch_bounds__(1024) void k_lstm(
    const ushort* __restrict__ Gc,
    const float* __restrict__ w_hh_f, const float* __restrict__ w_hh_b,
    ushort* __restrict__ hf, ushort* __restrict__ hb)
{
  __shared__ ushort h_lds[2][16][232];                 // 14,848 B
  __shared__ __align__(16) char wlds45[2][65536];      // kt4,kt5: gid*1024 + lane*16
  __shared__ __align__(16) char wlds6[17408];          // kt6: gid*256 + lo*16 (hi==0); [16384..17408) zeros

  const int tid = threadIdx.x;
  const int lane = tid & 63, w = tid >> 6;             // w = slot, 0..15
  const int lo = lane & 15, hi = lane >> 4;
  const bool hiHalf = lo >= 8;                         // owns cells i=2,3
  const int dir = blockIdx.x >> 3, grp = blockIdx.x & 7;
  const float* Whh = dir ? w_hh_b : w_hh_f;
  ushort* hout = dir ? hb : hf;

  for (int i = tid; i < 2 * 16 * 232; i += 1024) ((ushort*)h_lds)[i] = 0;
  if (tid < 256) ((uint*)(wlds6 + 16384))[tid] = 0;

  const int s = w;
  const int off = s < 12 ? 12 * s : 144 + 16 * (s - 12);
  const int cnt = s < 12 ? 12 : 16;
  const int rl  = min(cnt, 200 - off);

  short8 wreg[4][4];   // [gate][kt0..3]
  #pragma unroll
  for (int g = 0; g < 4; ++g) {
    const float sc = (g == 2) ? 2.f * L2E_ : L2E_;
    const float* wr = Whh + (size_t)(g * 200 + off + lo) * 200;
    const bool rowok = lo < rl;
    const int gid = s * 4 + g;
    #pragma unroll
    for (int kt = 0; kt < 7; ++kt) {
      const int k0 = kt * 32 + hi * 8;
      float v[8];
      if (rowok && k0 < 200) {
        float4 p0 = *(const float4*)(wr + k0);
        float4 p1 = *(const float4*)(wr + k0 + 4);
        v[0] = p0.x; v[1] = p0.y; v[2] = p0.z; v[3] = p0.w;
        v[4] = p1.x; v[5] = p1.y; v[6] = p1.z; v[7] = p1.w;
      } else {
        #pragma unroll
        for (int j = 0; j < 8; ++j) v[j] = 0.f;
      }
      short8 fr;
      #pragma unroll
      for (int j = 0; j < 8; ++j) fr[j] = (short)bf16bits(v[j] * sc);
      if (kt < 4) wreg[g][kt] = fr;
      else if (kt < 6) *(short8*)(wlds45[kt - 4] + gid * 1024 + lane * 16) = fr;
      else if (hi == 0) *(short8*)(wlds6 + gid * 256 + lo * 16) = fr;
    }
  }

  float c2_[2] = {0.f, 0.f};

  const int rowsel = lo & 7;
  const int step0 = dir ? (S_ - 1) : 0;
  const ushort* gpp = Gc + (size_t)(step0 * 64 + grp * 8 + rowsel) * NG_ + dir * G4_ + off + hi * 4;
  ushort* sp = hout + (size_t)(step0 * 64 + grp * 8 + rowsel) * H_ + off + hi * 4 + (hiHalf ? 2 : 0);
  const ptrdiff_t gstep = (dir ? -64 : 64) * (ptrdiff_t)NG_;
  const ptrdiff_t hstep = (dir ? -64 : 64) * (ptrdiff_t)H_;
  const bool cellok = (hi * 4 < rl);
  const int hwoff = rowsel * 464 + off * 2 + hi * 8 + (hiHalf ? 4 : 0);

  const char* base45a = wlds45[0] + s * 4096 + lane * 16;
  const char* base45b = wlds45[1] + s * 4096 + lane * 16;
  const char* base6   = wlds6 + ((hi == 0) ? (s * 1024 + lo * 16) : (16384 + lo * 16));

  __syncthreads();

  #pragma unroll 2
  for (int t = 0; t < S_; ++t) {
    const ushort (*HR)[232] = h_lds[t & 1];
    ushort (*HW)[232] = h_lds[(t & 1) ^ 1];

    uint2 pre[4];
    #pragma unroll
    for (int g = 0; g < 4; ++g)
      pre[g] = *(const uint2*)(gpp + g * 200);

    __builtin_amdgcn_s_setprio(1);
    f32x4 acc[4] = {};
    const char* hrow = (const char*)HR + lo * 464 + hi * 16;
    #pragma unroll
    for (int kt = 0; kt < 7; ++kt) {
      short8 hfr = *(const short8*)(hrow + kt * 64);
      if (kt < 4) {
        #pragma unroll
        for (int g = 0; g < 4; ++g)
          acc[g] = __builtin_amdgcn_mfma_f32_16x16x32_bf16(wreg[g][kt], hfr, acc[g], 0, 0, 0);
      } else if (kt == 4) {
        #pragma unroll
        for (int g = 0; g < 4; ++g) {
          short8 wk = *(const short8*)(base45a + g * 1024);
          acc[g] = __builtin_amdgcn_mfma_f32_16x16x32_bf16(wk, hfr, acc[g], 0, 0, 0);
        }
      } else if (kt == 5) {
        #pragma unroll
        for (int g = 0; g < 4; ++g) {
          short8 wk = *(const short8*)(base45b + g * 1024);
          acc[g] = __builtin_amdgcn_mfma_f32_16x16x32_bf16(wk, hfr, acc[g], 0, 0, 0);
        }
      } else {
        #pragma unroll
        for (int g = 0; g < 4; ++g) {
          short8 wk = *(const short8*)(base6 + g * 256);
          acc[g] = __builtin_amdgcn_mfma_f32_16x16x32_bf16(wk, hfr, acc[g], 0, 0, 0);
        }
      }
    }
    __builtin_amdgcn_s_setprio(0);

    const uint ui = hiHalf ? pre[0].y : pre[0].x;
    const uint uf = hiHalf ? pre[1].y : pre[1].x;
    const uint ug = hiHalf ? pre[2].y : pre[2].x;
    const uint uo = hiHalf ? pre[3].y : pre[3].x;
    const float aI0 = hiHalf ? acc[0][2] : acc[0][0];
    const float aI1 = hiHalf ? acc[0][3] : acc[0][1];
    const float aF0 = hiHalf ? acc[1][2] : acc[1][0];
    const float aF1 = hiHalf ? acc[1][3] : acc[1][1];
    const float aG0 = hiHalf ? acc[2][2] : acc[2][0];
    const float aG1 = hiHalf ? acc[2][3] : acc[2][1];
    const float aO0 = hiHalf ? acc[3][2] : acc[3][0];
    const float aO1 = hiHalf ? acc[3][3] : acc[3][1];

    float hv0, hv1;
    {
      float gi = aI0 + bf2f((ushort)ui);
      float gf = aF0 + bf2f((ushort)uf);
      float gg = aG0 + bf2f((ushort)ug);
      float go = aO0 + bf2f((ushort)uo);
      float cn = sig2(gf) * c2_[0] + sig2(gi) * (2.f * sig2(gg) - 1.f);
      c2_[0] = cn;
      hv0 = sig2(go) * (2.f * sig2(cn * (2.f * L2E_)) - 1.f);
    }
    {
      float gi = aI1 + bf2f((ushort)(ui >> 16));
      float gf = aF1 + bf2f((ushort)(uf >> 16));
      float gg = aG1 + bf2f((ushort)(ug >> 16));
      float go = aO1 + bf2f((ushort)(uo >> 16));
      float cn = sig2(gf) * c2_[1] + sig2(gi) * (2.f * sig2(gg) - 1.f);
      c2_[1] = cn;
      hv1 = sig2(go) * (2.f * sig2(cn * (2.f * L2E_)) - 1.f);
    }
    const uint pkw = (uint)bf16bits(hv0) | ((uint)bf16bits(hv1) << 16);
    if (cellok) {
      *(uint*)((char*)HW + hwoff) = pkw;
    }

    __syncthreads();

    if (cellok) *(uint*)sp = pkw;
    sp += hstep;
    gpp += gstep;
  }
}

// ---------------- K4: fused  tag = [hf|hb] @ Wo^T + out_b  ->  log_softmax over s ----------------
// One block per batch b. 512 thr = 8 waves: wave w -> token-row frag rfrag=w&3 of each
// 64-token tile, tag col-frags cpair=(w>>2)*2 + {0,1}. acc[8][2] f32x4 holds the full
// [512 s x 32 tag] slice in registers (static indexing). Softmax-over-s via 4KB LDS reduce.
__global__ __launch_bounds__(512) void k_out_lsm(
    const ushort* __restrict__ hf, const ushort* __restrict__ hb,
    const ushort* __restrict__ Wo, const float* __restrict__ out_b,
    float* __restrict__ out)
{
  __shared__ __align__(16) char Bs[65536];   // Wo: row*1024 + ((c^(row&7))<<4)
  __shared__ __align__(16) char As[65536];   // current 64-token tile, same layout
  __shared__ float red[64][17];
  __shared__ float mf[64], lsef[64];

  const int tid = threadIdx.x;
  const int lane = tid & 63, w = tid >> 6;
  const int lo4 = lane & 15, hi4 = lane >> 4;
  const int rfrag = w & 3;
  const int cpair = (w >> 2) * 2;
  const int b = blockIdx.x;
  const size_t n0 = (size_t)b * S_;

  // stage Wo (64 rows x 52 chunks)
  for (int s2 = tid; s2 < 64 * 52; s2 += 512) {
    int row = s2 / 52, c = s2 % 52;
    *(short8*)(Bs + row * 1024 + ((c ^ (row & 7)) << 4)) =
        *(const short8*)(Wo + (size_t)row * 416 + c * 8);
  }

  f32x4 acc[8][2] = {};
  #pragma unroll
  for (int it = 0; it < 8; ++it) {
    __syncthreads();   // it=0: nothing pending; it>0: previous tile reads done
    for (int s2 = tid; s2 < 64 * 52; s2 += 512) {
      int row = s2 / 52, c = s2 % 52;
      short8 v = {};
      const size_t n = n0 + it * 64 + row;
      if (c < 25)      v = *(const short8*)(hf + n * H_ + c * 8);
      else if (c < 50) v = *(const short8*)(hb + n * H_ + (c - 25) * 8);
      *(short8*)(As + row * 1024 + ((c ^ (row & 7)) << 4)) = v;
    }
    __syncthreads();
    #pragma unroll
    for (int kt = 0; kt < 13; ++kt) {
      const int ck = kt * 4 + hi4;
      const int ar = rfrag * 16 + lo4;
      short8 a = *(const short8*)(As + ar * 1024 + ((ck ^ (ar & 7)) << 4));
      #pragma unroll
      for (int cc = 0; cc < 2; ++cc) {
        const int br = (cpair + cc) * 16 + lo4;
        short8 bv = *(const short8*)(Bs + br * 1024 + ((ck ^ (br & 7)) << 4));
        acc[it][cc] = __builtin_amdgcn_mfma_f32_16x16x32_bf16(a, bv, acc[it][cc], 0, 0, 0);
      }
    }
  }

  // add bias (kept for bit-fidelity; it cancels in softmax-over-s)
  #pragma unroll
  for (int cc = 0; cc < 2; ++cc) {
    const float bb = out_b[(cpair + cc) * 16 + lo4];
    #pragma unroll
    for (int it = 0; it < 8; ++it)
      #pragma unroll
      for (int i = 0; i < 4; ++i) acc[it][cc][i] += bb;
  }

  // --- max over s ---
  #pragma unroll
  for (int cc = 0; cc < 2; ++cc) {
    float pm = -1e30f;
    #pragma unroll
    for (int it = 0; it < 8; ++it)
      #pragma unroll
      for (int i = 0; i < 4; ++i) pm = fmaxf(pm, acc[it][cc][i]);
    red[(cpair + cc) * 16 + lo4][rfrag * 4 + hi4] = pm;
  }
  __syncthreads();
  if (tid < 64) {
    float m = red[tid][0];
    #pragma unroll
    for (int k = 1; k < 16; ++k) m = fmaxf(m, red[tid][k]);
    mf[tid] = m;
  }
  __syncthreads();

  // --- sum exp over s ---
  #pragma unroll
  for (int cc = 0; cc < 2; ++cc) {
    const float m = mf[(cpair + cc) * 16 + lo4];
    float ps = 0.f;
    #pragma unroll
    for (int it = 0; it < 8; ++it)
      #pragma unroll
      for (int i = 0; i < 4; ++i) ps += exp2fast((acc[it][cc][i] - m) * L2E_);
    red[(cpair + cc) * 16 + lo4][rfrag * 4 + hi4] = ps;
  }
  __syncthreads();
  if (tid < 64) {
    float ssum = 0.f;
    #pragma unroll
    for (int k = 0; k < 16; ++k) ssum += red[tid][k];
    lsef[tid] = mf[tid] + logf(ssum);
  }
  __syncthreads();

  // --- write out = tag - lse ---
  #pragma unroll
  for (int cc = 0; cc < 2; ++cc) {
    const int t = (cpair + cc) * 16 + lo4;
    const float l = lsef[t];
    #pragma unroll
    for (int it = 0; it < 8; ++it)
      #pragma unroll
      for (int i = 0; i < 4; ++i) {
        const int sidx = it * 64 + rfrag * 16 + hi4 * 4 + i;
        out[(n0 + sidx) * T_ + t] = acc[it][cc][i] - l;
      }
  }
}

// ---------------- launch ----------------
extern "C" void kernel_launch(void* const* d_in, const int* in_sizes, int n_in,
                              void* d_out, int out_size, void* d_ws, size_t ws_size,
                              hipStream_t stream) {
  const int*   char_ids = (const int*)d_in[0];
  const int*   word_ids = (const int*)d_in[1];
  const float* word_emb = (const float*)d_in[2];
  const float* char_emb = (const float*)d_in[3];
  const float* conv_w   = (const float*)d_in[4];
  const float* conv_b   = (const float*)d_in[5];
  const float* w_ih_f   = (const float*)d_in[6];
  const float* w_hh_f   = (const float*)d_in[7];
  const float* b_ih_f   = (const float*)d_in[8];
  const float* b_hh_f   = (const float*)d_in[9];
  const float* w_ih_b   = (const float*)d_in[10];
  const float* w_hh_b   = (const float*)d_in[11];
  const float* b_ih_b   = (const float*)d_in[12];
  const float* b_hh_b   = (const float*)d_in[13];
  const float* out_w    = (const float*)d_in[14];
  const float* out_b    = (const float*)d_in[15];

  // ws layout (bytes)
  char* ws = (char*)d_ws;
  ushort* Xb    = (ushort*)(ws);                 // 16,777,216  [32768][256] bf16
  ushort* Wb    = (ushort*)(ws + 16777216);      //    851,968  [1664][256] bf16 (padded)
  float*  biasc = (float*) (ws + 17629184);      //      6,656  [1664] f32 (padded)
  ushort* Wo    = (ushort*)(ws + 17635840);      //     53,248  [64][416] bf16 (padded)
  ushort* Gc    = (ushort*)(ws + 18422016);      // 104,857,600 [32768][1600] bf16
  ushort* hf    = (ushort*)(ws + 123279616);     // 13,107,200  [32768][200] bf16
  ushort* hb    = (ushort*)(ws + 136386816);     // 13,107,200  -> total 149,494,016

  hipLaunchKernelGGL(k_build_x, dim3(N_ / 4), dim3(256), 0, stream,
                     char_ids, word_ids, word_emb, char_emb, conv_w, conv_b, Xb);
  hipLaunchKernelGGL(k_pack_w, dim3(NGP_ + T_), dim3(64), 0, stream,
                     w_ih_f, w_ih_b, b_ih_f, b_hh_f, b_ih_b, b_hh_b, out_w, Wb, biasc, Wo);
  hipLaunchKernelGGL(k_gemm_proj, dim3(NGP_ / 128, N_ / 128), dim3(512), 0, stream,
                     Xb, Wb, biasc, Gc);
  hipLaunchKernelGGL(k_lstm, dim3(16), dim3(1024), 0, stream, Gc, w_hh_f, w_hh_b, hf, hb);
  hipLaunchKernelGGL(k_out_lsm, dim3(B_), dim3(512), 0, stream, hf, hb, Wo, out_b, (float*)d_out);
}

// Round 16
// 1397.285 us; speedup vs baseline: 1.1367x; 1.0097x over previous
//
#include <hip/hip_runtime.h>
#include <hip/hip_bf16.h>
#include <math.h>

// dims
constexpr int B_ = 64, S_ = 512, LP_ = 18, CE_ = 10, LF_ = 32;
constexpr int WE_ = 200, H_ = 200, T_ = 64;
constexpr int N_ = B_ * S_;        // 32768 tokens, n = b*S + s = t*64 + j
constexpr int KP_ = 256;           // padded K for proj GEMM (232 -> 256)
constexpr int G4_ = 800;           // 4*H
constexpr int NG_ = 1600;          // both directions stacked
constexpr int NGP_ = 1664;         // padded to 13*128 for the 128-tile GEMM
constexpr float L2E_ = 1.4426950408889634f;

typedef short short8 __attribute__((ext_vector_type(8)));
typedef float f32x4 __attribute__((ext_vector_type(4)));

__device__ __forceinline__ ushort bf16bits(float v) {
  return __bfloat16_as_ushort(__float2bfloat16(v));
}
__device__ __forceinline__ float bf2f(ushort u) {
  return __uint_as_float(((uint)u) << 16);
}
__device__ __forceinline__ float exp2fast(float x) {
  float r; asm("v_exp_f32 %0, %1" : "=v"(r) : "v"(x)); return r;
}
// sigmoid with input pre-scaled by log2e:  sig2(y) = 1/(1+2^-y)
__device__ __forceinline__ float sig2(float y) {
  return __builtin_amdgcn_rcpf(1.f + exp2fast(-y));
}

// ---------------- K1: char CNN + embeddings -> Xb ; tail blocks pack Wb/biasc/Wo ----------------
// blocks [0, N_/4): build Xb (4 tokens each). blocks [N_/4, N_/4+NGP_+T_): packing.
__global__ __launch_bounds__(256) void k_build_pack(
    const int* __restrict__ char_ids, const int* __restrict__ word_ids,
    const float* __restrict__ word_emb, const float* __restrict__ char_emb,
    const float* __restrict__ conv_w, const float* __restrict__ conv_b,
    const float* __restrict__ w_ih_f, const float* __restrict__ w_ih_b,
    const float* __restrict__ b_ih_f, const float* __restrict__ b_hh_f,
    const float* __restrict__ b_ih_b, const float* __restrict__ b_hh_b,
    const float* __restrict__ out_w,
    ushort* __restrict__ Xb, ushort* __restrict__ Wb, float* __restrict__ biasc,
    ushort* __restrict__ Wo)
{
  if (blockIdx.x >= N_ / 4) {
    const int r = blockIdx.x - N_ / 4;   // 0..NGP_+T_-1
    if (r >= NGP_) {
      const int r2 = r - NGP_;           // 0..63 -> Wo
      for (int k = threadIdx.x; k < 416; k += 256)
        Wo[(size_t)r2 * 416 + k] = (k < 400) ? bf16bits(out_w[(size_t)r2 * 400 + k]) : (ushort)0;
      return;
    }
    if (r >= NG_) {
      for (int c = threadIdx.x; c < KP_; c += 256) Wb[(size_t)r * KP_ + c] = 0;
      if (threadIdx.x == 0) biasc[r] = 0.f;
      return;
    }
    const int rl = r < G4_ ? r : r - G4_;
    const int gate = rl / 200;
    const float sc = (gate == 2) ? 2.f * L2E_ : L2E_;
    const float* src = r < G4_ ? w_ih_f + (size_t)rl * 232 : w_ih_b + (size_t)rl * 232;
    for (int c = threadIdx.x; c < KP_; c += 256)
      Wb[(size_t)r * KP_ + c] = (c < 232) ? bf16bits(src[c] * sc) : (ushort)0;
    if (threadIdx.x == 0)
      biasc[r] = sc * (r < G4_ ? (b_ih_f[rl] + b_hh_f[rl]) : (b_ih_b[rl] + b_hh_b[rl]));
    return;
  }

  __shared__ float ce[4][LP_ * CE_];
  const int wave = threadIdx.x >> 6, lane = threadIdx.x & 63;
  const int n = blockIdx.x * 4 + wave;

  for (int i = lane; i < LP_ * CE_; i += 64) {
    int c = char_ids[n * LP_ + i / CE_];
    ce[wave][i] = char_emb[c * CE_ + (i % CE_)];
  }
  const float* we = word_emb + (size_t)word_ids[n] * WE_;
  ushort* xr = Xb + (size_t)n * KP_;
  if (lane < 50) {
    float4 p = *(const float4*)(we + lane * 4);
    ushort4 o;
    o.x = bf16bits(p.x); o.y = bf16bits(p.y); o.z = bf16bits(p.z); o.w = bf16bits(p.w);
    *(ushort4*)(xr + lane * 4) = o;
  }
  if (lane < KP_ - WE_ - LF_) xr[WE_ + LF_ + lane] = 0;   // pad cols 232..255
  __syncthreads();

  const int f = lane & 31, half = lane >> 5;
  float cw[30];
  #pragma unroll
  for (int i = 0; i < 30; ++i) cw[i] = conv_w[f * 30 + i];
  float m = -1e30f;
  for (int w = half * 8; w < half * 8 + 8; ++w) {
    float acc = 0.f;
    #pragma unroll
    for (int i = 0; i < 30; ++i) acc += ce[wave][w * CE_ + i] * cw[i];
    m = fmaxf(m, acc);
  }
  m = fmaxf(m, __shfl_xor(m, 32));
  if (half == 0) xr[WE_ + f] = bf16bits(m + conv_b[f]);
}

// ---------------- K2: MFMA GEMM  Gc[n][1600] = Xb @ Wb^T + bias (bf16 out) ----------------
// 128x128 tile, K=256 in one LDS stage. 512 thr = 8 waves, wave (wr,wc) owns 64x32.
// XCD-aware block swizzle (nwg = 3328 = 8 x 416 exactly): each XCD gets 32 row-tiles
// x 13 col-tiles -> A panels L2-local.
__global__ __launch_bounds__(512) void k_gemm_proj(
    const ushort* __restrict__ Xb, const ushort* __restrict__ Wb,
    const float* __restrict__ biasc, ushort* __restrict__ Gc)
{
  __shared__ __align__(16) char smem[131072];   // A: 0..64K (swz), B: 64K..128K (swz)
  const int tid = threadIdx.x;
  const int lane = tid & 63, w = tid >> 6;
  const int wr = w >> 2, wc = w & 3;

  // XCD swizzle: flat grid id -> contiguous chunk per XCD
  const int flat = blockIdx.y * 13 + blockIdx.x;     // 0..3327
  const int swz = (flat & 7) * 416 + (flat >> 3);    // bijective (3328 = 8*416)
  const int colbase = (swz % 13) * 128;
  const int rowbase = (swz / 13) * 128;

  const char* Ag = (const char*)(Xb + (size_t)rowbase * KP_);
  const char* Bg = (const char*)(Wb + (size_t)colbase * KP_);
  #pragma unroll
  for (int it = 0; it < 8; ++it) {
    int slot = it * 512 + tid;              // 0..4095
    int row = slot >> 5, c16 = slot & 31;
    int src = row * 512 + c16 * 16;
    int dst = row * 512 + ((c16 * 16) ^ ((row & 7) << 4));
    *(short8*)(smem + dst) = *(const short8*)(Ag + src);
    *(short8*)(smem + 65536 + dst) = *(const short8*)(Bg + src);
  }
  __syncthreads();

  f32x4 acc[4][2] = {};
  #pragma unroll
  for (int kk = 0; kk < 8; ++kk) {
    const int kb = kk * 64 + (lane >> 4) * 16;
    short8 a[4], b[2];
    #pragma unroll
    for (int m = 0; m < 4; ++m) {
      int ar = wr * 64 + m * 16 + (lane & 15);
      a[m] = *(const short8*)(smem + ar * 512 + (kb ^ ((ar & 7) << 4)));
    }
    #pragma unroll
    for (int n = 0; n < 2; ++n) {
      int bc = wc * 32 + n * 16 + (lane & 15);
      b[n] = *(const short8*)(smem + 65536 + bc * 512 + (kb ^ ((bc & 7) << 4)));
    }
    #pragma unroll
    for (int m = 0; m < 4; ++m)
      #pragma unroll
      for (int n = 0; n < 2; ++n)
        acc[m][n] = __builtin_amdgcn_mfma_f32_16x16x32_bf16(a[m], b[n], acc[m][n], 0, 0, 0);
  }
  __syncthreads();

  float* Cs = (float*)smem;
  #pragma unroll
  for (int m = 0; m < 4; ++m)
    #pragma unroll
    for (int n = 0; n < 2; ++n)
      #pragma unroll
      for (int i = 0; i < 4; ++i) {
        int r = wr * 64 + m * 16 + (lane >> 4) * 4 + i;
        int c = wc * 32 + n * 16 + (lane & 15);
        Cs[r * 132 + c] = acc[m][n][i];
      }
  __syncthreads();

  const int r = tid >> 2, cg = (tid & 3) * 32;
  ushort ob[32];
  #pragma unroll
  for (int j = 0; j < 32; ++j)
    ob[j] = bf16bits(Cs[r * 132 + cg + j] + biasc[colbase + cg + j]);
  const int colg = colbase + cg;
  ushort* dst = Gc + (size_t)(rowbase + r) * NG_ + colg;
  #pragma unroll
  for (int v = 0; v < 4; ++v)
    if (colg + v * 8 < NG_)
      *(short8*)(dst + v * 8) = *(short8*)(ob + v * 8);
}

// ---------------- K3: LSTM recurrence v12 (frozen champion, 1233 us) ----------------
__global__ __launch_bounds__(1024) void k_lstm(
    const ushort* __restrict__ Gc,
    const float* __restrict__ w_hh_f, const float* __restrict__ w_hh_b,
    ushort* __restrict__ hf, ushort* __restrict__ hb)
{
  __shared__ ushort h_lds[2][16][232];                 // 14,848 B
  __shared__ __align__(16) char wlds45[2][65536];      // kt4,kt5: gid*1024 + lane*16
  __shared__ __align__(16) char wlds6[17408];          // kt6: gid*256 + lo*16 (hi==0); [16384..17408) zeros

  const int tid = threadIdx.x;
  const int lane = tid & 63, w = tid >> 6;             // w = slot, 0..15
  const int lo = lane & 15, hi = lane >> 4;
  const bool hiHalf = lo >= 8;                         // owns cells i=2,3
  const int dir = blockIdx.x >> 3, grp = blockIdx.x & 7;
  const float* Whh = dir ? w_hh_b : w_hh_f;
  ushort* hout = dir ? hb : hf;

  for (int i = tid; i < 2 * 16 * 232; i += 1024) ((ushort*)h_lds)[i] = 0;
  if (tid < 256) ((uint*)(wlds6 + 16384))[tid] = 0;

  const int s = w;
  const int off = s < 12 ? 12 * s : 144 + 16 * (s - 12);
  const int cnt = s < 12 ? 12 : 16;
  const int rl  = min(cnt, 200 - off);

  short8 wreg[4][4];   // [gate][kt0..3]
  #pragma unroll
  for (int g = 0; g < 4; ++g) {
    const float sc = (g == 2) ? 2.f * L2E_ : L2E_;
    const float* wr = Whh + (size_t)(g * 200 + off + lo) * 200;
    const bool rowok = lo < rl;
    const int gid = s * 4 + g;
    #pragma unroll
    for (int kt = 0; kt < 7; ++kt) {
      const int k0 = kt * 32 + hi * 8;
      float v[8];
      if (rowok && k0 < 200) {
        float4 p0 = *(const float4*)(wr + k0);
        float4 p1 = *(const float4*)(wr + k0 + 4);
        v[0] = p0.x; v[1] = p0.y; v[2] = p0.z; v[3] = p0.w;
        v[4] = p1.x; v[5] = p1.y; v[6] = p1.z; v[7] = p1.w;
      } else {
        #pragma unroll
        for (int j = 0; j < 8; ++j) v[j] = 0.f;
      }
      short8 fr;
      #pragma unroll
      for (int j = 0; j < 8; ++j) fr[j] = (short)bf16bits(v[j] * sc);
      if (kt < 4) wreg[g][kt] = fr;
      else if (kt < 6) *(short8*)(wlds45[kt - 4] + gid * 1024 + lane * 16) = fr;
      else if (hi == 0) *(short8*)(wlds6 + gid * 256 + lo * 16) = fr;
    }
  }

  float c2_[2] = {0.f, 0.f};

  const int rowsel = lo & 7;
  const int step0 = dir ? (S_ - 1) : 0;
  const ushort* gpp = Gc + (size_t)(step0 * 64 + grp * 8 + rowsel) * NG_ + dir * G4_ + off + hi * 4;
  ushort* sp = hout + (size_t)(step0 * 64 + grp * 8 + rowsel) * H_ + off + hi * 4 + (hiHalf ? 2 : 0);
  const ptrdiff_t gstep = (dir ? -64 : 64) * (ptrdiff_t)NG_;
  const ptrdiff_t hstep = (dir ? -64 : 64) * (ptrdiff_t)H_;
  const bool cellok = (hi * 4 < rl);
  const int hwoff = rowsel * 464 + off * 2 + hi * 8 + (hiHalf ? 4 : 0);

  const char* base45a = wlds45[0] + s * 4096 + lane * 16;
  const char* base45b = wlds45[1] + s * 4096 + lane * 16;
  const char* base6   = wlds6 + ((hi == 0) ? (s * 1024 + lo * 16) : (16384 + lo * 16));

  __syncthreads();

  #pragma unroll 2
  for (int t = 0; t < S_; ++t) {
    const ushort (*HR)[232] = h_lds[t & 1];
    ushort (*HW)[232] = h_lds[(t & 1) ^ 1];

    uint2 pre[4];
    #pragma unroll
    for (int g = 0; g < 4; ++g)
      pre[g] = *(const uint2*)(gpp + g * 200);

    __builtin_amdgcn_s_setprio(1);
    f32x4 acc[4] = {};
    const char* hrow = (const char*)HR + lo * 464 + hi * 16;
    #pragma unroll
    for (int kt = 0; kt < 7; ++kt) {
      short8 hfr = *(const short8*)(hrow + kt * 64);
      if (kt < 4) {
        #pragma unroll
        for (int g = 0; g < 4; ++g)
          acc[g] = __builtin_amdgcn_mfma_f32_16x16x32_bf16(wreg[g][kt], hfr, acc[g], 0, 0, 0);
      } else if (kt == 4) {
        #pragma unroll
        for (int g = 0; g < 4; ++g) {
          short8 wk = *(const short8*)(base45a + g * 1024);
          acc[g] = __builtin_amdgcn_mfma_f32_16x16x32_bf16(wk, hfr, acc[g], 0, 0, 0);
        }
      } else if (kt == 5) {
        #pragma unroll
        for (int g = 0; g < 4; ++g) {
          short8 wk = *(const short8*)(base45b + g * 1024);
          acc[g] = __builtin_amdgcn_mfma_f32_16x16x32_bf16(wk, hfr, acc[g], 0, 0, 0);
        }
      } else {
        #pragma unroll
        for (int g = 0; g < 4; ++g) {
          short8 wk = *(const short8*)(base6 + g * 256);
          acc[g] = __builtin_amdgcn_mfma_f32_16x16x32_bf16(wk, hfr, acc[g], 0, 0, 0);
        }
      }
    }
    __builtin_amdgcn_s_setprio(0);

    const uint ui = hiHalf ? pre[0].y : pre[0].x;
    const uint uf = hiHalf ? pre[1].y : pre[1].x;
    const uint ug = hiHalf ? pre[2].y : pre[2].x;
    const uint uo = hiHalf ? pre[3].y : pre[3].x;
    const float aI0 = hiHalf ? acc[0][2] : acc[0][0];
    const float aI1 = hiHalf ? acc[0][3] : acc[0][1];
    const float aF0 = hiHalf ? acc[1][2] : acc[1][0];
    const float aF1 = hiHalf ? acc[1][3] : acc[1][1];
    const float aG0 = hiHalf ? acc[2][2] : acc[2][0];
    const float aG1 = hiHalf ? acc[2][3] : acc[2][1];
    const float aO0 = hiHalf ? acc[3][2] : acc[3][0];
    const float aO1 = hiHalf ? acc[3][3] : acc[3][1];

    float hv0, hv1;
    {
      float gi = aI0 + bf2f((ushort)ui);
      float gf = aF0 + bf2f((ushort)uf);
      float gg = aG0 + bf2f((ushort)ug);
      float go = aO0 + bf2f((ushort)uo);
      float cn = sig2(gf) * c2_[0] + sig2(gi) * (2.f * sig2(gg) - 1.f);
      c2_[0] = cn;
      hv0 = sig2(go) * (2.f * sig2(cn * (2.f * L2E_)) - 1.f);
    }
    {
      float gi = aI1 + bf2f((ushort)(ui >> 16));
      float gf = aF1 + bf2f((ushort)(uf >> 16));
      float gg = aG1 + bf2f((ushort)(ug >> 16));
      float go = aO1 + bf2f((ushort)(uo >> 16));
      float cn = sig2(gf) * c2_[1] + sig2(gi) * (2.f * sig2(gg) - 1.f);
      c2_[1] = cn;
      hv1 = sig2(go) * (2.f * sig2(cn * (2.f * L2E_)) - 1.f);
    }
    const uint pkw = (uint)bf16bits(hv0) | ((uint)bf16bits(hv1) << 16);
    if (cellok) {
      *(uint*)((char*)HW + hwoff) = pkw;
    }

    __syncthreads();

    if (cellok) *(uint*)sp = pkw;
    sp += hstep;
    gpp += gstep;
  }
}

// ---------------- K4: fused  tag = [hf|hb] @ Wo^T + out_b  ->  log_softmax over s ----------------
__global__ __launch_bounds__(512) void k_out_lsm(
    const ushort* __restrict__ hf, const ushort* __restrict__ hb,
    const ushort* __restrict__ Wo, const float* __restrict__ out_b,
    float* __restrict__ out)
{
  __shared__ __align__(16) char Bs[65536];   // Wo: row*1024 + ((c^(row&7))<<4)
  __shared__ __align__(16) char As[65536];   // current 64-token tile, same layout
  __shared__ float red[64][17];
  __shared__ float mf[64], lsef[64];

  const int tid = threadIdx.x;
  const int lane = tid & 63, w = tid >> 6;
  const int lo4 = lane & 15, hi4 = lane >> 4;
  const int rfrag = w & 3;
  const int cpair = (w >> 2) * 2;
  const int b = blockIdx.x;
  const size_t n0 = (size_t)b * S_;

  for (int s2 = tid; s2 < 64 * 52; s2 += 512) {
    int row = s2 / 52, c = s2 % 52;
    *(short8*)(Bs + row * 1024 + ((c ^ (row & 7)) << 4)) =
        *(const short8*)(Wo + (size_t)row * 416 + c * 8);
  }

  f32x4 acc[8][2] = {};
  #pragma unroll
  for (int it = 0; it < 8; ++it) {
    __syncthreads();
    for (int s2 = tid; s2 < 64 * 52; s2 += 512) {
      int row = s2 / 52, c = s2 % 52;
      short8 v = {};
      const size_t n = n0 + it * 64 + row;
      if (c < 25)      v = *(const short8*)(hf + n * H_ + c * 8);
      else if (c < 50) v = *(const short8*)(hb + n * H_ + (c - 25) * 8);
      *(short8*)(As + row * 1024 + ((c ^ (row & 7)) << 4)) = v;
    }
    __syncthreads();
    #pragma unroll
    for (int kt = 0; kt < 13; ++kt) {
      const int ck = kt * 4 + hi4;
      const int ar = rfrag * 16 + lo4;
      short8 a = *(const short8*)(As + ar * 1024 + ((ck ^ (ar & 7)) << 4));
      #pragma unroll
      for (int cc = 0; cc < 2; ++cc) {
        const int br = (cpair + cc) * 16 + lo4;
        short8 bv = *(const short8*)(Bs + br * 1024 + ((ck ^ (br & 7)) << 4));
        acc[it][cc] = __builtin_amdgcn_mfma_f32_16x16x32_bf16(a, bv, acc[it][cc], 0, 0, 0);
      }
    }
  }

  #pragma unroll
  for (int cc = 0; cc < 2; ++cc) {
    const float bb = out_b[(cpair + cc) * 16 + lo4];
    #pragma unroll
    for (int it = 0; it < 8; ++it)
      #pragma unroll
      for (int i = 0; i < 4; ++i) acc[it][cc][i] += bb;
  }

  #pragma unroll
  for (int cc = 0; cc < 2; ++cc) {
    float pm = -1e30f;
    #pragma unroll
    for (int it = 0; it < 8; ++it)
      #pragma unroll
      for (int i = 0; i < 4; ++i) pm = fmaxf(pm, acc[it][cc][i]);
    red[(cpair + cc) * 16 + lo4][rfrag * 4 + hi4] = pm;
  }
  __syncthreads();
  if (tid < 64) {
    float m = red[tid][0];
    #pragma unroll
    for (int k = 1; k < 16; ++k) m = fmaxf(m, red[tid][k]);
    mf[tid] = m;
  }
  __syncthreads();

  #pragma unroll
  for (int cc = 0; cc < 2; ++cc) {
    const float m = mf[(cpair + cc) * 16 + lo4];
    float ps = 0.f;
    #pragma unroll
    for (int it = 0; it < 8; ++it)
      #pragma unroll
      for (int i = 0; i < 4; ++i) ps += exp2fast((acc[it][cc][i] - m) * L2E_);
    red[(cpair + cc) * 16 + lo4][rfrag * 4 + hi4] = ps;
  }
  __syncthreads();
  if (tid < 64) {
    float ssum = 0.f;
    #pragma unroll
    for (int k = 0; k < 16; ++k) ssum += red[tid][k];
    lsef[tid] = mf[tid] + logf(ssum);
  }
  __syncthreads();

  #pragma unroll
  for (int cc = 0; cc < 2; ++cc) {
    const int t = (cpair + cc) * 16 + lo4;
    const float l = lsef[t];
    #pragma unroll
    for (int it = 0; it < 8; ++it)
      #pragma unroll
      for (int i = 0; i < 4; ++i) {
        const int sidx = it * 64 + rfrag * 16 + hi4 * 4 + i;
        out[(n0 + sidx) * T_ + t] = acc[it][cc][i] - l;
      }
  }
}

// ---------------- launch ----------------
extern "C" void kernel_launch(void* const* d_in, const int* in_sizes, int n_in,
                              void* d_out, int out_size, void* d_ws, size_t ws_size,
                              hipStream_t stream) {
  const int*   char_ids = (const int*)d_in[0];
  const int*   word_ids = (const int*)d_in[1];
  const float* word_emb = (const float*)d_in[2];
  const float* char_emb = (const float*)d_in[3];
  const float* conv_w   = (const float*)d_in[4];
  const float* conv_b   = (const float*)d_in[5];
  const float* w_ih_f   = (const float*)d_in[6];
  const float* w_hh_f   = (const float*)d_in[7];
  const float* b_ih_f   = (const float*)d_in[8];
  const float* b_hh_f   = (const float*)d_in[9];
  const float* w_ih_b   = (const float*)d_in[10];
  const float* w_hh_b   = (const float*)d_in[11];
  const float* b_ih_b   = (const float*)d_in[12];
  const float* b_hh_b   = (const float*)d_in[13];
  const float* out_w    = (const float*)d_in[14];
  const float* out_b    = (const float*)d_in[15];

  // ws layout (bytes)
  char* ws = (char*)d_ws;
  ushort* Xb    = (ushort*)(ws);                 // 16,777,216  [32768][256] bf16
  ushort* Wb    = (ushort*)(ws + 16777216);      //    851,968  [1664][256] bf16 (padded)
  float*  biasc = (float*) (ws + 17629184);      //      6,656  [1664] f32 (padded)
  ushort* Wo    = (ushort*)(ws + 17635840);      //     53,248  [64][416] bf16 (padded)
  ushort* Gc    = (ushort*)(ws + 18422016);      // 104,857,600 [32768][1600] bf16
  ushort* hf    = (ushort*)(ws + 123279616);     // 13,107,200  [32768][200] bf16
  ushort* hb    = (ushort*)(ws + 136386816);     // 13,107,200  -> total 149,494,016

  hipLaunchKernelGGL(k_build_pack, dim3(N_ / 4 + NGP_ + T_), dim3(256), 0, stream,
                     char_ids, word_ids, word_emb, char_emb, conv_w, conv_b,
                     w_ih_f, w_ih_b, b_ih_f, b_hh_f, b_ih_b, b_hh_b, out_w,
                     Xb, Wb, biasc, Wo);
  hipLaunchKernelGGL(k_gemm_proj, dim3(13, N_ / 128), dim3(512), 0, stream,
                     Xb, Wb, biasc, Gc);
  hipLaunchKernelGGL(k_lstm, dim3(16), dim3(1024), 0, stream, Gc, w_hh_f, w_hh_b, hf, hb);
  hipLaunchKernelGGL(k_out_lsm, dim3(B_), dim3(512), 0, stream, hf, hb, Wo, out_b, (float*)d_out);
}